// Round 5
// baseline (476.983 us; speedup 1.0000x reference)
//
#include <hip/hip_runtime.h>
#include <hip/hip_bf16.h>

#define NN 1024
#define MM 1024
#define DX 64
#define DY 16
#define HH 128

#define EPSF   1e-7f
#define LOG2E  1.4426950408889634f
#define LN2    0.6931471805599453f
#define K2     14426950.408889634f   /* LOG2E / EPS */
#define LNM    6.9314718055994531f   /* ln(1024) */

typedef __bf16          bf16x8_t __attribute__((ext_vector_type(8)));
typedef float           f32x4_t  __attribute__((ext_vector_type(4)));
typedef unsigned short  u16x8_t  __attribute__((ext_vector_type(8)));

__device__ __forceinline__ unsigned short f2bf(float f) {
    unsigned int u = __float_as_uint(f);
    u += 0x7fffu + ((u >> 16) & 1u);          // round-to-nearest-even
    return (unsigned short)(u >> 16);
}

// log2(1 + 2^s)  == softplus(x)/ln2 with s = x*log2e  (scaling folded upstream)
__device__ __forceinline__ float l2e1(float s) {
    return __builtin_amdgcn_logf(1.0f + __builtin_amdgcn_exp2f(s));
}

// ---------------- prep: hx*log2e(+b1), hu*log2e, W2^T -> bf16, costN[n][m] ----
__global__ void prep(const float* __restrict__ X, const float* __restrict__ U,
                     const float* __restrict__ Y, const float* __restrict__ W1,
                     const float* __restrict__ b1, const float* __restrict__ W2,
                     float* __restrict__ hx, float* __restrict__ hu,
                     unsigned short* __restrict__ w2t, float* __restrict__ costN)
{
    const int blk = blockIdx.x, tid = threadIdx.x;   // 128 threads
    if (blk < NN) {
        const int n = blk, h = tid;
        float acc = b1[h];
        #pragma unroll 8
        for (int d = 0; d < DX; ++d) acc += X[n*DX+d] * W1[d*HH+h];
        hx[n*HH+h] = acc * LOG2E;
    } else if (blk < NN+MM) {
        const int m = blk - NN, h = tid;
        float acc = 0.f;
        #pragma unroll
        for (int d = 0; d < DY; ++d) acc += U[m*DY+d] * W1[(DX+d)*HH+h];
        hu[m*HH+h] = acc * LOG2E;
    } else if (blk < NN+MM+HH) {
        const int c = blk - (NN+MM), k = tid;        // w2t[c][k] = W2[k][c]
        w2t[c*HH+k] = f2bf(W2[k*HH+c]);
    } else {
        const int n = blk - (NN+MM+HH);
        const float4* Yv = reinterpret_cast<const float4*>(&Y[n*DY]);
        const float4 y0 = Yv[0], y1 = Yv[1], y2 = Yv[2], y3 = Yv[3];
        #pragma unroll
        for (int r = 0; r < MM/128; ++r) {
            const int m = tid + r*128;
            const float4* Uv = reinterpret_cast<const float4*>(&U[m*DY]);
            const float4 u0 = Uv[0], u1 = Uv[1], u2 = Uv[2], u3 = Uv[3];
            float acc = y0.x*u0.x + y0.y*u0.y + y0.z*u0.z + y0.w*u0.w
                      + y1.x*u1.x + y1.y*u1.y + y1.z*u1.z + y1.w*u1.w
                      + y2.x*u2.x + y2.y*u2.y + y2.z*u2.z + y2.w*u2.w
                      + y3.x*u3.x + y3.y*u3.y + y3.z*u3.z + y3.w*u3.w;
            costN[n*MM+m] = acc;                     // costN[n][m] = Y[n]·U[m]
        }
    }
}

// ---------------- main fused kernel ----------------
// 1024 blocks x 256 threads (4 waves). nb = (bid>>1)*2 owns n in {nb,nb+1};
// half = bid&1 owns m in [half*512, +512) as 8 chunks of 64. Wave w processes
// M-tiles T = 2w+t SEQUENTIALLY (t=0,1) so only 8 f32x4 accumulators are live
// (R3 lesson: 16 accs + 32-reg hx hoist -> 192-reg granule -> 2 waves/SIMD +
// ~85 KB/block scratch spill). hx slice comes from a 1 KB LDS buffer instead
// of registers. Target <=128 total regs -> 3-4 waves/SIMD, zero spill.
__global__ __launch_bounds__(256, 3) void
otmain(const float* __restrict__ hx, const float* __restrict__ hu,
       const unsigned short* __restrict__ w2t,
       const float* __restrict__ b2, const float* __restrict__ W3,
       const float* __restrict__ b3, const float* __restrict__ costN,
       float2* __restrict__ part)
{
    __shared__ unsigned short w2s[HH*HH];    // 32 KB, XOR-swizzled bf16 W2^T
    __shared__ float hxs[2][HH+4];           // +4 pad: il rows hit different banks
    __shared__ float red[4][2][2];

    const int tid  = threadIdx.x;
    const int lane = tid & 63;
    const int w    = tid >> 6;
    const int nb   = (blockIdx.x >> 1) * 2;
    const int half = blockIdx.x & 1;

    // stage 2 hx rows (1 KB)
    hxs[tid >> 7][tid & 127] = hx[(nb + (tid >> 7))*HH + (tid & 127)];

    // stage W2^T into LDS; swizzle byte ^= ((row&7)<<4) to kill the 256B-stride
    // 16-way bank conflict on ds_read_b128
    #pragma unroll
    for (int it = 0; it < 8; ++it) {
        const int chunk = tid + it*256;
        const int lin   = chunk << 4;
        const int c     = lin >> 8;
        const int swz   = lin ^ ((c & 7) << 4);
        *reinterpret_cast<u16x8_t*>(reinterpret_cast<char*>(w2s) + swz) =
            *reinterpret_cast<const u16x8_t*>(reinterpret_cast<const char*>(w2t) + lin);
    }

    const int il = lane & 1;           // n-local index for A rows (pair&1)
    const int jl = (lane >> 1) & 7;    // j-within-tile for A rows (pair>>1)
    const int g  = lane >> 4;          // k-group (A/B) and row-group (C)
    const int cl = lane & 15;          // col (B/C)

    float b2v[8], w3v[8];
    #pragma unroll
    for (int nt = 0; nt < 8; ++nt) {
        b2v[nt] = b2[nt*16+cl] * LOG2E;   // pre-activation in log2-domain
        w3v[nt] = W3[nt*16+cl] * LN2;     // fold softplus ln2 back here
    }
    const float b3v = b3[0];

    float mx[4], sv[4];
    #pragma unroll
    for (int q = 0; q < 4; ++q) { mx[q] = -3.0e38f; sv[q] = 0.f; }

    __syncthreads();

    for (int cc = 0; cc < 8; ++cc) {
        const int mb = (half*8 + cc) * 64;
        #pragma unroll
        for (int t = 0; t < 2; ++t) {
            const int m0 = mb + 16*w + 8*t + jl;   // A-row m for tile T=2w+t
            f32x4_t acc[8];
            #pragma unroll
            for (int nt = 0; nt < 8; ++nt)
                #pragma unroll
                for (int q = 0; q < 4; ++q) acc[nt][q] = 0.f;

            #pragma unroll
            for (int ks = 0; ks < 4; ++ks) {
                const int kf = ks*32 + g*8;
                const float4 ua = *reinterpret_cast<const float4*>(&hu[m0*HH + kf]);
                const float4 ub = *reinterpret_cast<const float4*>(&hu[m0*HH + kf + 4]);
                const float4 ha = *reinterpret_cast<const float4*>(&hxs[il][kf]);
                const float4 hb = *reinterpret_cast<const float4*>(&hxs[il][kf + 4]);
                bf16x8_t a0;
                a0[0]=(__bf16)l2e1(ha.x+ua.x); a0[1]=(__bf16)l2e1(ha.y+ua.y);
                a0[2]=(__bf16)l2e1(ha.z+ua.z); a0[3]=(__bf16)l2e1(ha.w+ua.w);
                a0[4]=(__bf16)l2e1(hb.x+ub.x); a0[5]=(__bf16)l2e1(hb.y+ub.y);
                a0[6]=(__bf16)l2e1(hb.z+ub.z); a0[7]=(__bf16)l2e1(hb.w+ub.w);

                #pragma unroll
                for (int nt = 0; nt < 8; ++nt) {
                    const int cidx = nt*16 + cl;
                    const int off  = (cidx*256 + ks*64 + g*16) ^ ((cidx & 7) << 4);
                    const bf16x8_t bfr = *reinterpret_cast<const bf16x8_t*>(
                            reinterpret_cast<const char*>(w2s) + off);
                    acc[nt] = __builtin_amdgcn_mfma_f32_16x16x32_bf16(a0, bfr, acc[nt], 0, 0, 0);
                }
            }

            // epilogue tile t: layer2 softplus + W3 dot -> phi, then online LSE
            float phi0=0.f, phi1=0.f, phi2=0.f, phi3=0.f;
            #pragma unroll
            for (int nt = 0; nt < 8; ++nt) {
                phi0 += l2e1(acc[nt][0] + b2v[nt]) * w3v[nt];
                phi1 += l2e1(acc[nt][1] + b2v[nt]) * w3v[nt];
                phi2 += l2e1(acc[nt][2] + b2v[nt]) * w3v[nt];
                phi3 += l2e1(acc[nt][3] + b2v[nt]) * w3v[nt];
            }
            #pragma unroll
            for (int st = 1; st < 16; st <<= 1) {
                phi0 += __shfl_xor(phi0, st, 64);
                phi1 += __shfl_xor(phi1, st, 64);
                phi2 += __shfl_xor(phi2, st, 64);
                phi3 += __shfl_xor(phi3, st, 64);
            }
            // C rows r = 4g+q -> pair p = 16T + r: i = q&1 (n), j = 8T+2g+(q>>1)
            const int jm = mb + 16*w + 8*t + 2*g;
            const float2 c0 = *reinterpret_cast<const float2*>(&costN[nb*MM + jm]);
            const float2 c1 = *reinterpret_cast<const float2*>(&costN[(nb+1)*MM + jm]);
            const float dv0 = c0.x - (phi0 + b3v);
            const float dv1 = c1.x - (phi1 + b3v);
            const float dv2 = c0.y - (phi2 + b3v);
            const float dv3 = c1.y - (phi3 + b3v);
            // single-transcendental online LSE update
            #define UPD(q, d) { const float mo = mx[q]; const float mn = fmaxf(mo, (d)); \
                const float e = __builtin_amdgcn_exp2f(K2*(fminf(mo,(d))-mn)); \
                sv[q] = ((d) <= mo) ? (sv[q] + e) : (sv[q]*e + 1.f); mx[q] = mn; }
            UPD(0, dv0) UPD(1, dv1) UPD(2, dv2) UPD(3, dv3)
            #undef UPD
        }
    }

    // fold q and q+2 (same n, disjoint m-subsets) into 2 channels
    float fmx[2], fs[2];
    #pragma unroll
    for (int i = 0; i < 2; ++i) {
        const float m1v = mx[i], m2v = mx[i+2];
        const float Mv  = fmaxf(m1v, m2v);
        fmx[i] = Mv;
        fs[i]  = sv[i]  *__builtin_amdgcn_exp2f(K2*(m1v-Mv))
               + sv[i+2]*__builtin_amdgcn_exp2f(K2*(m2v-Mv));
    }
    // lanes within a 16-lane cl-group are exact duplicates: count s once
    if (cl != 0) { fs[0] = 0.f; fs[1] = 0.f; }
    #pragma unroll
    for (int st = 1; st < 64; st <<= 1) {
        #pragma unroll
        for (int i = 0; i < 2; ++i) {
            const float om = __shfl_xor(fmx[i], st, 64);
            const float os = __shfl_xor(fs[i],  st, 64);
            const float Mv = fmaxf(fmx[i], om);
            fs[i]  = fs[i]*__builtin_amdgcn_exp2f(K2*(fmx[i]-Mv))
                   + os  *__builtin_amdgcn_exp2f(K2*(om-Mv));
            fmx[i] = Mv;
        }
    }
    if (lane == 0) {
        red[w][0][0] = fmx[0]; red[w][0][1] = fs[0];
        red[w][1][0] = fmx[1]; red[w][1][1] = fs[1];
    }
    __syncthreads();
    if (tid < 2) {
        float Mv = red[0][tid][0], Sv = red[0][tid][1];
        #pragma unroll
        for (int ww = 1; ww < 4; ++ww) {
            const float om = red[ww][tid][0], os = red[ww][tid][1];
            const float M2 = fmaxf(Mv, om);
            Sv = Sv*__builtin_amdgcn_exp2f(K2*(Mv-M2))
               + os*__builtin_amdgcn_exp2f(K2*(om-M2));
            Mv = M2;
        }
        part[(nb + tid)*2 + half] = make_float2(Mv, Sv);
    }
}

// ---------------- merge the two m-halves per n ----------------
__global__ void merge(const float2* __restrict__ part, float* __restrict__ out)
{
    const int n = blockIdx.x*256 + threadIdx.x;
    if (n >= NN) return;
    const float2 p0 = part[n*2+0], p1 = part[n*2+1];
    const float M = fmaxf(p0.x, p1.x);
    const float S = p0.y*__builtin_amdgcn_exp2f(K2*(p0.x-M))
                  + p1.y*__builtin_amdgcn_exp2f(K2*(p1.x-M));
    out[n] = M + EPSF*(LN2*__builtin_amdgcn_logf(S) - LNM);
}

extern "C" void kernel_launch(void* const* d_in, const int* in_sizes, int n_in,
                              void* d_out, int out_size, void* d_ws, size_t ws_size,
                              hipStream_t stream)
{
    const float* X  = (const float*)d_in[0];
    const float* U  = (const float*)d_in[1];
    const float* Y  = (const float*)d_in[2];
    const float* W1 = (const float*)d_in[3];
    const float* b1 = (const float*)d_in[4];
    const float* W2 = (const float*)d_in[5];
    const float* b2 = (const float*)d_in[6];
    const float* W3 = (const float*)d_in[7];
    const float* b3 = (const float*)d_in[8];
    float* out = (float*)d_out;

    char* ws = (char*)d_ws;
    float*          hx    = (float*)(ws);                    // 512 KB
    float*          hu    = (float*)(ws + 524288);           // 512 KB
    unsigned short* w2t   = (unsigned short*)(ws + 1048576); // 32 KB
    float*          costN = (float*)(ws + 1081344);          // 4 MB
    float2*         part  = (float2*)(ws + 5275648);         // 16 KB

    prep<<<dim3(3200), dim3(128), 0, stream>>>(X, U, Y, W1, b1, W2, hx, hu, w2t, costN);
    otmain<<<dim3(1024), dim3(256), 0, stream>>>(hx, hu, w2t, b2, W3, b3, costN, part);
    merge<<<dim3(4), dim3(256), 0, stream>>>(part, out);
}

// Round 8
// 228.082 us; speedup vs baseline: 2.0913x; 2.0913x over previous
//
#include <hip/hip_runtime.h>
#include <hip/hip_bf16.h>

#define NN 1024
#define MM 1024
#define DX 64
#define DY 16
#define HH 128

#define EPSF   1e-7f
#define LOG2E  1.4426950408889634f
#define LN2    0.6931471805599453f
#define K2     14426950.408889634f   /* LOG2E / EPS */
#define LNM    6.9314718055994531f   /* ln(1024) */

typedef __bf16          bf16x8_t __attribute__((ext_vector_type(8)));
typedef float           f32x4_t  __attribute__((ext_vector_type(4)));
typedef unsigned short  u16x8_t  __attribute__((ext_vector_type(8)));

__device__ __forceinline__ unsigned short f2bf(float f) {
    unsigned int u = __float_as_uint(f);
    u += 0x7fffu + ((u >> 16) & 1u);          // round-to-nearest-even
    return (unsigned short)(u >> 16);
}

// log2(1 + 2^s)  == softplus(x)/ln2 with s = x*log2e  (scaling folded upstream)
__device__ __forceinline__ float l2e1(float s) {
    return __builtin_amdgcn_logf(1.0f + __builtin_amdgcn_exp2f(s));
}

// ---------------- prep: hx*log2e(+b1), hu*log2e, W2^T -> bf16, costN[n][m] ----
__global__ void prep(const float* __restrict__ X, const float* __restrict__ U,
                     const float* __restrict__ Y, const float* __restrict__ W1,
                     const float* __restrict__ b1, const float* __restrict__ W2,
                     float* __restrict__ hx, float* __restrict__ hu,
                     unsigned short* __restrict__ w2t, float* __restrict__ costN)
{
    const int blk = blockIdx.x, tid = threadIdx.x;   // 128 threads
    if (blk < NN) {
        const int n = blk, h = tid;
        float acc = b1[h];
        #pragma unroll 8
        for (int d = 0; d < DX; ++d) acc += X[n*DX+d] * W1[d*HH+h];
        hx[n*HH+h] = acc * LOG2E;
    } else if (blk < NN+MM) {
        const int m = blk - NN, h = tid;
        float acc = 0.f;
        #pragma unroll
        for (int d = 0; d < DY; ++d) acc += U[m*DY+d] * W1[(DX+d)*HH+h];
        hu[m*HH+h] = acc * LOG2E;
    } else if (blk < NN+MM+HH) {
        const int c = blk - (NN+MM), k = tid;        // w2t[c][k] = W2[k][c]
        w2t[c*HH+k] = f2bf(W2[k*HH+c]);
    } else {
        const int n = blk - (NN+MM+HH);
        const float4* Yv = reinterpret_cast<const float4*>(&Y[n*DY]);
        const float4 y0 = Yv[0], y1 = Yv[1], y2 = Yv[2], y3 = Yv[3];
        #pragma unroll
        for (int r = 0; r < MM/128; ++r) {
            const int m = tid + r*128;
            const float4* Uv = reinterpret_cast<const float4*>(&U[m*DY]);
            const float4 u0 = Uv[0], u1 = Uv[1], u2 = Uv[2], u3 = Uv[3];
            float acc = y0.x*u0.x + y0.y*u0.y + y0.z*u0.z + y0.w*u0.w
                      + y1.x*u1.x + y1.y*u1.y + y1.z*u1.z + y1.w*u1.w
                      + y2.x*u2.x + y2.y*u2.y + y2.z*u2.z + y2.w*u2.w
                      + y3.x*u3.x + y3.y*u3.y + y3.z*u3.z + y3.w*u3.w;
            costN[n*MM+m] = acc;                     // costN[n][m] = Y[n]·U[m]
        }
    }
}

// ---------------- main fused kernel ----------------
// 1024 blocks x 256 threads (4 waves). nb = (bid>>1)*2 owns n in {nb,nb+1};
// half = bid&1 owns m in [half*512, +512) as 8 chunks of 64. Wave w processes
// M-tiles T = 2w+t SEQUENTIALLY (t=0,1): only 8 f32x4 accumulators live, hx
// slice in a 1 KB LDS buffer. Natural demand ~140-160 regs total.
//
// launch_bounds(256,2) ON PURPOSE: R2 (cap 64) and R5 (cap 84) both proved
// that any min-waves >=3 forces allocation below the natural working set and
// spills 300-900 MB of scratch per dispatch. Occupancy must come from the
// structure being light, not from the cap.
__global__ __launch_bounds__(256, 2) void
otmain(const float* __restrict__ hx, const float* __restrict__ hu,
       const unsigned short* __restrict__ w2t,
       const float* __restrict__ b2, const float* __restrict__ W3,
       const float* __restrict__ b3, const float* __restrict__ costN,
       float2* __restrict__ part)
{
    __shared__ unsigned short w2s[HH*HH];    // 32 KB, XOR-swizzled bf16 W2^T
    __shared__ float hxs[2][HH+4];           // +4 pad: il rows hit different banks
    __shared__ float red[4][2][2];

    const int tid  = threadIdx.x;
    const int lane = tid & 63;
    const int w    = tid >> 6;
    const int nb   = (blockIdx.x >> 1) * 2;
    const int half = blockIdx.x & 1;

    // stage 2 hx rows (1 KB)
    hxs[tid >> 7][tid & 127] = hx[(nb + (tid >> 7))*HH + (tid & 127)];

    // stage W2^T into LDS; swizzle byte ^= ((row&7)<<4) to kill the 256B-stride
    // 16-way bank conflict on ds_read_b128
    #pragma unroll
    for (int it = 0; it < 8; ++it) {
        const int chunk = tid + it*256;
        const int lin   = chunk << 4;
        const int c     = lin >> 8;
        const int swz   = lin ^ ((c & 7) << 4);
        *reinterpret_cast<u16x8_t*>(reinterpret_cast<char*>(w2s) + swz) =
            *reinterpret_cast<const u16x8_t*>(reinterpret_cast<const char*>(w2t) + lin);
    }

    const int il = lane & 1;           // n-local index for A rows (pair&1)
    const int jl = (lane >> 1) & 7;    // j-within-tile for A rows (pair>>1)
    const int g  = lane >> 4;          // k-group (A/B) and row-group (C)
    const int cl = lane & 15;          // col (B/C)

    float b2v[8], w3v[8];
    #pragma unroll
    for (int nt = 0; nt < 8; ++nt) {
        b2v[nt] = b2[nt*16+cl] * LOG2E;   // pre-activation in log2-domain
        w3v[nt] = W3[nt*16+cl] * LN2;     // fold softplus ln2 back here
    }
    const float b3v = b3[0];

    float mx[4], sv[4];
    #pragma unroll
    for (int q = 0; q < 4; ++q) { mx[q] = -3.0e38f; sv[q] = 0.f; }

    __syncthreads();

    for (int cc = 0; cc < 8; ++cc) {
        const int mb = (half*8 + cc) * 64;
        #pragma unroll
        for (int t = 0; t < 2; ++t) {
            const int m0 = mb + 16*w + 8*t + jl;   // A-row m for tile T=2w+t
            f32x4_t acc[8];
            #pragma unroll
            for (int nt = 0; nt < 8; ++nt)
                #pragma unroll
                for (int q = 0; q < 4; ++q) acc[nt][q] = 0.f;

            #pragma unroll
            for (int ks = 0; ks < 4; ++ks) {
                const int kf = ks*32 + g*8;
                const float4 ua = *reinterpret_cast<const float4*>(&hu[m0*HH + kf]);
                const float4 ub = *reinterpret_cast<const float4*>(&hu[m0*HH + kf + 4]);
                const float4 ha = *reinterpret_cast<const float4*>(&hxs[il][kf]);
                const float4 hb = *reinterpret_cast<const float4*>(&hxs[il][kf + 4]);
                bf16x8_t a0;
                a0[0]=(__bf16)l2e1(ha.x+ua.x); a0[1]=(__bf16)l2e1(ha.y+ua.y);
                a0[2]=(__bf16)l2e1(ha.z+ua.z); a0[3]=(__bf16)l2e1(ha.w+ua.w);
                a0[4]=(__bf16)l2e1(hb.x+ub.x); a0[5]=(__bf16)l2e1(hb.y+ub.y);
                a0[6]=(__bf16)l2e1(hb.z+ub.z); a0[7]=(__bf16)l2e1(hb.w+ub.w);

                #pragma unroll
                for (int nt = 0; nt < 8; ++nt) {
                    const int cidx = nt*16 + cl;
                    const int off  = (cidx*256 + ks*64 + g*16) ^ ((cidx & 7) << 4);
                    const bf16x8_t bfr = *reinterpret_cast<const bf16x8_t*>(
                            reinterpret_cast<const char*>(w2s) + off);
                    acc[nt] = __builtin_amdgcn_mfma_f32_16x16x32_bf16(a0, bfr, acc[nt], 0, 0, 0);
                }
            }

            // epilogue tile t: layer2 softplus + W3 dot -> phi, then online LSE
            float phi0=0.f, phi1=0.f, phi2=0.f, phi3=0.f;
            #pragma unroll
            for (int nt = 0; nt < 8; ++nt) {
                phi0 += l2e1(acc[nt][0] + b2v[nt]) * w3v[nt];
                phi1 += l2e1(acc[nt][1] + b2v[nt]) * w3v[nt];
                phi2 += l2e1(acc[nt][2] + b2v[nt]) * w3v[nt];
                phi3 += l2e1(acc[nt][3] + b2v[nt]) * w3v[nt];
            }
            #pragma unroll
            for (int st = 1; st < 16; st <<= 1) {
                phi0 += __shfl_xor(phi0, st, 64);
                phi1 += __shfl_xor(phi1, st, 64);
                phi2 += __shfl_xor(phi2, st, 64);
                phi3 += __shfl_xor(phi3, st, 64);
            }
            // C rows r = 4g+q -> pair p = 16T + r: i = q&1 (n), j = 8T+2g+(q>>1)
            const int jm = mb + 16*w + 8*t + 2*g;
            const float2 c0 = *reinterpret_cast<const float2*>(&costN[nb*MM + jm]);
            const float2 c1 = *reinterpret_cast<const float2*>(&costN[(nb+1)*MM + jm]);
            const float dv0 = c0.x - (phi0 + b3v);
            const float dv1 = c1.x - (phi1 + b3v);
            const float dv2 = c0.y - (phi2 + b3v);
            const float dv3 = c1.y - (phi3 + b3v);
            // single-transcendental online LSE update
            #define UPD(q, d) { const float mo = mx[q]; const float mn = fmaxf(mo, (d)); \
                const float e = __builtin_amdgcn_exp2f(K2*(fminf(mo,(d))-mn)); \
                sv[q] = ((d) <= mo) ? (sv[q] + e) : (sv[q]*e + 1.f); mx[q] = mn; }
            UPD(0, dv0) UPD(1, dv1) UPD(2, dv2) UPD(3, dv3)
            #undef UPD
        }
    }

    // fold q and q+2 (same n, disjoint m-subsets) into 2 channels
    float fmx[2], fs[2];
    #pragma unroll
    for (int i = 0; i < 2; ++i) {
        const float m1v = mx[i], m2v = mx[i+2];
        const float Mv  = fmaxf(m1v, m2v);
        fmx[i] = Mv;
        fs[i]  = sv[i]  *__builtin_amdgcn_exp2f(K2*(m1v-Mv))
               + sv[i+2]*__builtin_amdgcn_exp2f(K2*(m2v-Mv));
    }
    // lanes within a 16-lane cl-group are exact duplicates: count s once
    if (cl != 0) { fs[0] = 0.f; fs[1] = 0.f; }
    #pragma unroll
    for (int st = 1; st < 64; st <<= 1) {
        #pragma unroll
        for (int i = 0; i < 2; ++i) {
            const float om = __shfl_xor(fmx[i], st, 64);
            const float os = __shfl_xor(fs[i],  st, 64);
            const float Mv = fmaxf(fmx[i], om);
            fs[i]  = fs[i]*__builtin_amdgcn_exp2f(K2*(fmx[i]-Mv))
                   + os  *__builtin_amdgcn_exp2f(K2*(om-Mv));
            fmx[i] = Mv;
        }
    }
    if (lane == 0) {
        red[w][0][0] = fmx[0]; red[w][0][1] = fs[0];
        red[w][1][0] = fmx[1]; red[w][1][1] = fs[1];
    }
    __syncthreads();
    if (tid < 2) {
        float Mv = red[0][tid][0], Sv = red[0][tid][1];
        #pragma unroll
        for (int ww = 1; ww < 4; ++ww) {
            const float om = red[ww][tid][0], os = red[ww][tid][1];
            const float M2 = fmaxf(Mv, om);
            Sv = Sv*__builtin_amdgcn_exp2f(K2*(Mv-M2))
               + os*__builtin_amdgcn_exp2f(K2*(om-M2));
            Mv = M2;
        }
        part[(nb + tid)*2 + half] = make_float2(Mv, Sv);
    }
}

// ---------------- merge the two m-halves per n ----------------
__global__ void merge(const float2* __restrict__ part, float* __restrict__ out)
{
    const int n = blockIdx.x*256 + threadIdx.x;
    if (n >= NN) return;
    const float2 p0 = part[n*2+0], p1 = part[n*2+1];
    const float M = fmaxf(p0.x, p1.x);
    const float S = p0.y*__builtin_amdgcn_exp2f(K2*(p0.x-M))
                  + p1.y*__builtin_amdgcn_exp2f(K2*(p1.x-M));
    out[n] = M + EPSF*(LN2*__builtin_amdgcn_logf(S) - LNM);
}

extern "C" void kernel_launch(void* const* d_in, const int* in_sizes, int n_in,
                              void* d_out, int out_size, void* d_ws, size_t ws_size,
                              hipStream_t stream)
{
    const float* X  = (const float*)d_in[0];
    const float* U  = (const float*)d_in[1];
    const float* Y  = (const float*)d_in[2];
    const float* W1 = (const float*)d_in[3];
    const float* b1 = (const float*)d_in[4];
    const float* W2 = (const float*)d_in[5];
    const float* b2 = (const float*)d_in[6];
    const float* W3 = (const float*)d_in[7];
    const float* b3 = (const float*)d_in[8];
    float* out = (float*)d_out;

    char* ws = (char*)d_ws;
    float*          hx    = (float*)(ws);                    // 512 KB
    float*          hu    = (float*)(ws + 524288);           // 512 KB
    unsigned short* w2t   = (unsigned short*)(ws + 1048576); // 32 KB
    float*          costN = (float*)(ws + 1081344);          // 4 MB
    float2*         part  = (float2*)(ws + 5275648);         // 16 KB

    prep<<<dim3(3200), dim3(128), 0, stream>>>(X, U, Y, W1, b1, W2, hx, hu, w2t, costN);
    otmain<<<dim3(1024), dim3(256), 0, stream>>>(hx, hu, w2t, b2, W3, b3, costN, part);
    merge<<<dim3(4), dim3(256), 0, stream>>>(part, out);
}

// Round 11
// 169.072 us; speedup vs baseline: 2.8212x; 1.3490x over previous
//
#include <hip/hip_runtime.h>
#include <hip/hip_bf16.h>

#define NN 1024
#define MM 1024
#define DX 64
#define DY 16
#define HH 128

#define EPSF   1e-7f
#define LOG2E  1.4426950408889634f
#define LN2    0.6931471805599453f
#define K2     14426950.408889634f   /* LOG2E / EPS */
#define LNM    6.9314718055994531f   /* ln(1024) */

typedef __bf16          bf16x8_t __attribute__((ext_vector_type(8)));
typedef float           f32x4_t  __attribute__((ext_vector_type(4)));
typedef unsigned short  u16x8_t  __attribute__((ext_vector_type(8)));

__device__ __forceinline__ unsigned short f2bf(float f) {
    unsigned int u = __float_as_uint(f);
    u += 0x7fffu + ((u >> 16) & 1u);          // round-to-nearest-even
    return (unsigned short)(u >> 16);
}

// log2(1 + 2^s)  == softplus(x)/ln2 with s = x*log2e  (scaling folded upstream)
__device__ __forceinline__ float l2e1(float s) {
    return __builtin_amdgcn_logf(1.0f + __builtin_amdgcn_exp2f(s));
}

// ---------------- prep: hx*log2e(+b1), hu*log2e, W2^T -> bf16, costN[n][m] ----
__global__ void prep(const float* __restrict__ X, const float* __restrict__ U,
                     const float* __restrict__ Y, const float* __restrict__ W1,
                     const float* __restrict__ b1, const float* __restrict__ W2,
                     float* __restrict__ hx, float* __restrict__ hu,
                     unsigned short* __restrict__ w2t, float* __restrict__ costN)
{
    const int blk = blockIdx.x, tid = threadIdx.x;   // 128 threads
    if (blk < NN) {
        const int n = blk, h = tid;
        float acc = b1[h];
        #pragma unroll 8
        for (int d = 0; d < DX; ++d) acc += X[n*DX+d] * W1[d*HH+h];
        hx[n*HH+h] = acc * LOG2E;
    } else if (blk < NN+MM) {
        const int m = blk - NN, h = tid;
        float acc = 0.f;
        #pragma unroll
        for (int d = 0; d < DY; ++d) acc += U[m*DY+d] * W1[(DX+d)*HH+h];
        hu[m*HH+h] = acc * LOG2E;
    } else if (blk < NN+MM+HH) {
        const int c = blk - (NN+MM), k = tid;        // w2t[c][k] = W2[k][c]
        w2t[c*HH+k] = f2bf(W2[k*HH+c]);
    } else {
        const int n = blk - (NN+MM+HH);
        const float4* Yv = reinterpret_cast<const float4*>(&Y[n*DY]);
        const float4 y0 = Yv[0], y1 = Yv[1], y2 = Yv[2], y3 = Yv[3];
        #pragma unroll
        for (int r = 0; r < MM/128; ++r) {
            const int m = tid + r*128;
            const float4* Uv = reinterpret_cast<const float4*>(&U[m*DY]);
            const float4 u0 = Uv[0], u1 = Uv[1], u2 = Uv[2], u3 = Uv[3];
            float acc = y0.x*u0.x + y0.y*u0.y + y0.z*u0.z + y0.w*u0.w
                      + y1.x*u1.x + y1.y*u1.y + y1.z*u1.z + y1.w*u1.w
                      + y2.x*u2.x + y2.y*u2.y + y2.z*u2.z + y2.w*u2.w
                      + y3.x*u3.x + y3.y*u3.y + y3.z*u3.z + y3.w*u3.w;
            costN[n*MM+m] = acc;                     // costN[n][m] = Y[n]·U[m]
        }
    }
}

// ---------------- main fused kernel ----------------
// 1024 blocks x 256 threads (4 waves). nb = (bid>>1)*2 owns n in {nb,nb+1};
// half = bid&1 owns m in [half*512, +512) as 8 chunks of 64. Wave w processes
// M-tiles T = 2w+t with a TRUE sequential loop (unroll 1): one acc[8] set
// (32 regs) live at a time.
//
// R8 lesson: LLVM derives its VGPR budget from LDS occupancy (34 KB -> 4
// blocks/CU -> 4 waves/EU -> 128 VGPRs) and IGNORES a looser launch_bounds.
// The previous `#pragma unroll` on the t loop let the scheduler interleave
// both tiles (~160 live regs) -> 184 MB/dispatch scratch spill. unroll 1 on
// cc and t keeps the live set ~100 regs < 128 -> zero spill is the goal.
__global__ __launch_bounds__(256, 2) void
otmain(const float* __restrict__ hx, const float* __restrict__ hu,
       const unsigned short* __restrict__ w2t,
       const float* __restrict__ b2, const float* __restrict__ W3,
       const float* __restrict__ b3, const float* __restrict__ costN,
       float2* __restrict__ part)
{
    __shared__ unsigned short w2s[HH*HH];    // 32 KB, XOR-swizzled bf16 W2^T
    __shared__ float hxs[2][HH+4];           // +4 pad: il rows hit different banks
    __shared__ float red[4][2][2];

    const int tid  = threadIdx.x;
    const int lane = tid & 63;
    const int w    = tid >> 6;
    const int nb   = (blockIdx.x >> 1) * 2;
    const int half = blockIdx.x & 1;

    // stage 2 hx rows (1 KB)
    hxs[tid >> 7][tid & 127] = hx[(nb + (tid >> 7))*HH + (tid & 127)];

    // stage W2^T into LDS; swizzle byte ^= ((row&7)<<4) to kill the 256B-stride
    // 16-way bank conflict on ds_read_b128
    #pragma unroll
    for (int it = 0; it < 8; ++it) {
        const int chunk = tid + it*256;
        const int lin   = chunk << 4;
        const int c     = lin >> 8;
        const int swz   = lin ^ ((c & 7) << 4);
        *reinterpret_cast<u16x8_t*>(reinterpret_cast<char*>(w2s) + swz) =
            *reinterpret_cast<const u16x8_t*>(reinterpret_cast<const char*>(w2t) + lin);
    }

    const int il = lane & 1;           // n-local index for A rows (pair&1)
    const int jl = (lane >> 1) & 7;    // j-within-tile for A rows (pair>>1)
    const int g  = lane >> 4;          // k-group (A/B) and row-group (C)
    const int cl = lane & 15;          // col (B/C)

    float b2v[8], w3v[8];
    #pragma unroll
    for (int nt = 0; nt < 8; ++nt) {
        b2v[nt] = b2[nt*16+cl] * LOG2E;   // pre-activation in log2-domain
        w3v[nt] = W3[nt*16+cl] * LN2;     // fold softplus ln2 back here
    }
    const float b3v = b3[0];

    float mx[4], sv[4];
    #pragma unroll
    for (int q = 0; q < 4; ++q) { mx[q] = -3.0e38f; sv[q] = 0.f; }

    __syncthreads();

    #pragma unroll 1
    for (int cc = 0; cc < 8; ++cc) {
        const int mb = (half*8 + cc) * 64;
        #pragma unroll 1
        for (int t = 0; t < 2; ++t) {
            const int m0 = mb + 16*w + 8*t + jl;   // A-row m for tile T=2w+t
            f32x4_t acc[8];
            #pragma unroll
            for (int nt = 0; nt < 8; ++nt)
                #pragma unroll
                for (int q = 0; q < 4; ++q) acc[nt][q] = 0.f;

            #pragma unroll
            for (int ks = 0; ks < 4; ++ks) {
                const int kf = ks*32 + g*8;
                const float4 ua = *reinterpret_cast<const float4*>(&hu[m0*HH + kf]);
                const float4 ub = *reinterpret_cast<const float4*>(&hu[m0*HH + kf + 4]);
                const float4 ha = *reinterpret_cast<const float4*>(&hxs[il][kf]);
                const float4 hb = *reinterpret_cast<const float4*>(&hxs[il][kf + 4]);
                bf16x8_t a0;
                a0[0]=(__bf16)l2e1(ha.x+ua.x); a0[1]=(__bf16)l2e1(ha.y+ua.y);
                a0[2]=(__bf16)l2e1(ha.z+ua.z); a0[3]=(__bf16)l2e1(ha.w+ua.w);
                a0[4]=(__bf16)l2e1(hb.x+ub.x); a0[5]=(__bf16)l2e1(hb.y+ub.y);
                a0[6]=(__bf16)l2e1(hb.z+ub.z); a0[7]=(__bf16)l2e1(hb.w+ub.w);

                #pragma unroll
                for (int nt = 0; nt < 8; ++nt) {
                    const int cidx = nt*16 + cl;
                    const int off  = (cidx*256 + ks*64 + g*16) ^ ((cidx & 7) << 4);
                    const bf16x8_t bfr = *reinterpret_cast<const bf16x8_t*>(
                            reinterpret_cast<const char*>(w2s) + off);
                    acc[nt] = __builtin_amdgcn_mfma_f32_16x16x32_bf16(a0, bfr, acc[nt], 0, 0, 0);
                }
            }

            // epilogue tile t: layer2 softplus + W3 dot -> phi, then online LSE
            float phi0=0.f, phi1=0.f, phi2=0.f, phi3=0.f;
            #pragma unroll
            for (int nt = 0; nt < 8; ++nt) {
                phi0 += l2e1(acc[nt][0] + b2v[nt]) * w3v[nt];
                phi1 += l2e1(acc[nt][1] + b2v[nt]) * w3v[nt];
                phi2 += l2e1(acc[nt][2] + b2v[nt]) * w3v[nt];
                phi3 += l2e1(acc[nt][3] + b2v[nt]) * w3v[nt];
            }
            #pragma unroll
            for (int st = 1; st < 16; st <<= 1) {
                phi0 += __shfl_xor(phi0, st, 64);
                phi1 += __shfl_xor(phi1, st, 64);
                phi2 += __shfl_xor(phi2, st, 64);
                phi3 += __shfl_xor(phi3, st, 64);
            }
            // C rows r = 4g+q -> pair p = 16T + r: i = q&1 (n), j = 8T+2g+(q>>1)
            const int jm = mb + 16*w + 8*t + 2*g;
            const float2 c0 = *reinterpret_cast<const float2*>(&costN[nb*MM + jm]);
            const float2 c1 = *reinterpret_cast<const float2*>(&costN[(nb+1)*MM + jm]);
            const float dv0 = c0.x - (phi0 + b3v);
            const float dv1 = c1.x - (phi1 + b3v);
            const float dv2 = c0.y - (phi2 + b3v);
            const float dv3 = c1.y - (phi3 + b3v);
            // single-transcendental online LSE update
            #define UPD(q, d) { const float mo = mx[q]; const float mn = fmaxf(mo, (d)); \
                const float e = __builtin_amdgcn_exp2f(K2*(fminf(mo,(d))-mn)); \
                sv[q] = ((d) <= mo) ? (sv[q] + e) : (sv[q]*e + 1.f); mx[q] = mn; }
            UPD(0, dv0) UPD(1, dv1) UPD(2, dv2) UPD(3, dv3)
            #undef UPD
        }
    }

    // fold q and q+2 (same n, disjoint m-subsets) into 2 channels
    float fmx[2], fs[2];
    #pragma unroll
    for (int i = 0; i < 2; ++i) {
        const float m1v = mx[i], m2v = mx[i+2];
        const float Mv  = fmaxf(m1v, m2v);
        fmx[i] = Mv;
        fs[i]  = sv[i]  *__builtin_amdgcn_exp2f(K2*(m1v-Mv))
               + sv[i+2]*__builtin_amdgcn_exp2f(K2*(m2v-Mv));
    }
    // lanes within a 16-lane cl-group are exact duplicates: count s once
    if (cl != 0) { fs[0] = 0.f; fs[1] = 0.f; }
    #pragma unroll
    for (int st = 1; st < 64; st <<= 1) {
        #pragma unroll
        for (int i = 0; i < 2; ++i) {
            const float om = __shfl_xor(fmx[i], st, 64);
            const float os = __shfl_xor(fs[i],  st, 64);
            const float Mv = fmaxf(fmx[i], om);
            fs[i]  = fs[i]*__builtin_amdgcn_exp2f(K2*(fmx[i]-Mv))
                   + os  *__builtin_amdgcn_exp2f(K2*(om-Mv));
            fmx[i] = Mv;
        }
    }
    if (lane == 0) {
        red[w][0][0] = fmx[0]; red[w][0][1] = fs[0];
        red[w][1][0] = fmx[1]; red[w][1][1] = fs[1];
    }
    __syncthreads();
    if (tid < 2) {
        float Mv = red[0][tid][0], Sv = red[0][tid][1];
        #pragma unroll
        for (int ww = 1; ww < 4; ++ww) {
            const float om = red[ww][tid][0], os = red[ww][tid][1];
            const float M2 = fmaxf(Mv, om);
            Sv = Sv*__builtin_amdgcn_exp2f(K2*(Mv-M2))
               + os*__builtin_amdgcn_exp2f(K2*(om-M2));
            Mv = M2;
        }
        part[(nb + tid)*2 + half] = make_float2(Mv, Sv);
    }
}

// ---------------- merge the two m-halves per n ----------------
__global__ void merge(const float2* __restrict__ part, float* __restrict__ out)
{
    const int n = blockIdx.x*256 + threadIdx.x;
    if (n >= NN) return;
    const float2 p0 = part[n*2+0], p1 = part[n*2+1];
    const float M = fmaxf(p0.x, p1.x);
    const float S = p0.y*__builtin_amdgcn_exp2f(K2*(p0.x-M))
                  + p1.y*__builtin_amdgcn_exp2f(K2*(p1.x-M));
    out[n] = M + EPSF*(LN2*__builtin_amdgcn_logf(S) - LNM);
}

extern "C" void kernel_launch(void* const* d_in, const int* in_sizes, int n_in,
                              void* d_out, int out_size, void* d_ws, size_t ws_size,
                              hipStream_t stream)
{
    const float* X  = (const float*)d_in[0];
    const float* U  = (const float*)d_in[1];
    const float* Y  = (const float*)d_in[2];
    const float* W1 = (const float*)d_in[3];
    const float* b1 = (const float*)d_in[4];
    const float* W2 = (const float*)d_in[5];
    const float* b2 = (const float*)d_in[6];
    const float* W3 = (const float*)d_in[7];
    const float* b3 = (const float*)d_in[8];
    float* out = (float*)d_out;

    char* ws = (char*)d_ws;
    float*          hx    = (float*)(ws);                    // 512 KB
    float*          hu    = (float*)(ws + 524288);           // 512 KB
    unsigned short* w2t   = (unsigned short*)(ws + 1048576); // 32 KB
    float*          costN = (float*)(ws + 1081344);          // 4 MB
    float2*         part  = (float2*)(ws + 5275648);         // 16 KB

    prep<<<dim3(3200), dim3(128), 0, stream>>>(X, U, Y, W1, b1, W2, hx, hu, w2t, costN);
    otmain<<<dim3(1024), dim3(256), 0, stream>>>(hx, hu, w2t, b2, W3, b3, costN, part);
    merge<<<dim3(4), dim3(256), 0, stream>>>(part, out);
}